// Round 9
// baseline (706.859 us; speedup 1.0000x reference)
//
#include <hip/hip_runtime.h>
#include <hip/hip_bf16.h>

#define H_DIM 1024
#define I_DIM 2816
#define NE 8
#define T_TOK 8192
#define RMAX 18432          // 16384 + 8*256 padding (256-aligned expert segments)

// control ws offsets (bytes)
#define WS_ROUTE_CNT 0
#define WS_CURSOR    32
#define WS_PO        64
#define WS_TOP1      128
#define WS_PSUM      160
#define WS_RECIDX    256
#define WS_RECW0     33024
#define WS_RECW1     65792
#define WS_POS0      98560
#define WS_POS1      131328
#define WS_TOKID     164096

constexpr size_t WS_XG  = 1ull << 20;
constexpr size_t XG_SZ  = (size_t)RMAX * H_DIM * 2;       // 37.7 MB
constexpr size_t W_SZ   = (size_t)NE * I_DIM * H_DIM * 2; // 46.1 MB
constexpr size_t WS_WGB = WS_XG + XG_SZ;
constexpr size_t WS_WUB = WS_WGB + W_SZ;
constexpr size_t WS_WDB = WS_WUB + W_SZ;
constexpr size_t WS_ACT = WS_WDB + W_SZ;                  // 103.8 MB
constexpr size_t WS_Y   = WS_XG;                          // yseg overlays xg

typedef __attribute__((ext_vector_type(8))) short short8;
typedef __attribute__((ext_vector_type(4))) float f32x4;

#define GLOAD16(g, l) __builtin_amdgcn_global_load_lds( \
    (const __attribute__((address_space(1))) void*)(g), \
    (__attribute__((address_space(3))) void*)(l), 16, 0, 0)

#define FENCE() asm volatile("" ::: "memory")
#define BARX() do { FENCE(); __builtin_amdgcn_s_barrier(); FENCE(); } while (0)
#define VMC(N) asm volatile("s_waitcnt vmcnt(" #N ")" ::: "memory")

static __device__ __forceinline__ short f2bf(float f) {
  return (short)__builtin_bit_cast(unsigned short, (__bf16)f);
}
static __device__ __forceinline__ float bf2f(short s) {
  return __builtin_bit_cast(float, ((unsigned)(unsigned short)s) << 16);
}

static __device__ __forceinline__ short8 pack8(const float* __restrict__ p) {
  float4 a = *(const float4*)p;
  float4 b = *(const float4*)(p + 4);
  short8 v;
  v[0] = f2bf(a.x); v[1] = f2bf(a.y); v[2] = f2bf(a.z); v[3] = f2bf(a.w);
  v[4] = f2bf(b.x); v[5] = f2bf(b.y); v[6] = f2bf(b.z); v[7] = f2bf(b.w);
  return v;
}

// ---------------- router ---------------------------------------------------
__global__ __launch_bounds__(256) void k_router(const float* __restrict__ x,
                                                const float* __restrict__ gw,
                                                char* __restrict__ ws) {
  int tid = threadIdx.x;
  int lane = tid & 63;
  int wv = tid >> 6;
  int t = blockIdx.x * 4 + wv;

  float acc[NE];
#pragma unroll
  for (int e = 0; e < NE; ++e) acc[e] = 0.f;
  const float* xr = x + (size_t)t * H_DIM;
#pragma unroll
  for (int k = 0; k < H_DIM / 64; ++k) {
    float xv = xr[k * 64 + lane];
#pragma unroll
    for (int e = 0; e < NE; ++e) acc[e] += xv * gw[e * H_DIM + k * 64 + lane];
  }
#pragma unroll
  for (int e = 0; e < NE; ++e) {
#pragma unroll
    for (int off = 32; off; off >>= 1) acc[e] += __shfl_xor(acc[e], off);
  }

  __shared__ float s_ps[NE], s_c1[NE];
  __shared__ int s_rc[NE];
  if (tid < NE) { s_ps[tid] = 0.f; s_c1[tid] = 0.f; s_rc[tid] = 0; }
  __syncthreads();

  int* recIdx = (int*)(ws + WS_RECIDX);
  float* recW0 = (float*)(ws + WS_RECW0);
  float* recW1 = (float*)(ws + WS_RECW1);

  if (lane == 0) {
    float mx = acc[0];
#pragma unroll
    for (int e = 1; e < NE; ++e) mx = fmaxf(mx, acc[e]);
    float p[NE], s = 0.f;
#pragma unroll
    for (int e = 0; e < NE; ++e) { p[e] = expf(acc[e] - mx); s += p[e]; }
    float inv = 1.f / s;
#pragma unroll
    for (int e = 0; e < NE; ++e) p[e] *= inv;
    int i0 = 0;
#pragma unroll
    for (int e = 1; e < NE; ++e) if (p[e] > p[i0]) i0 = e;
    int i1 = (i0 == 0) ? 1 : 0;
#pragma unroll
    for (int e = 0; e < NE; ++e) if (e != i0 && p[e] > p[i1]) i1 = e;
    float w0 = p[i0], w1 = p[i1];
    float sm = fmaxf(w0 + w1, 1e-8f);
    w0 /= sm; w1 /= sm;
    recIdx[t] = i0 | (i1 << 8);
    recW0[t] = w0;
    recW1[t] = w1;
    atomicAdd(&s_c1[i0], 1.f);
#pragma unroll
    for (int e = 0; e < NE; ++e) atomicAdd(&s_ps[e], p[e]);
    atomicAdd(&s_rc[i0], 1);
    atomicAdd(&s_rc[i1], 1);
  }
  __syncthreads();
  if (tid < NE) {
    atomicAdd((float*)(ws + WS_PSUM) + tid, s_ps[tid]);
    atomicAdd((float*)(ws + WS_TOP1) + tid, s_c1[tid]);
    atomicAdd((int*)(ws + WS_ROUTE_CNT) + tid, s_rc[tid]);
  }
}

// ---------------- offsets (256-padded) + aux -------------------------------
__global__ void k_offsets(char* __restrict__ ws, float* __restrict__ out_aux) {
  if (threadIdx.x == 0) {
    int* rc = (int*)(ws + WS_ROUTE_CNT);
    int* po = (int*)(ws + WS_PO);
    int acc = 0;
    for (int e = 0; e < NE; ++e) {
      po[e] = acc;
      acc += ((rc[e] + 255) / 256) * 256;
    }
    po[NE] = acc;
    float* c1 = (float*)(ws + WS_TOP1);
    float* ps = (float*)(ws + WS_PSUM);
    float aux = 0.f;
    for (int e = 0; e < NE; ++e)
      aux += (c1[e] / (float)T_TOK) * (ps[e] / (float)T_TOK);
    out_aux[0] = aux * (float)NE;
  }
}

// ---------------- assign ----------------------------------------------------
__global__ __launch_bounds__(256) void k_assign(char* __restrict__ ws) {
  int t = blockIdx.x * 256 + threadIdx.x;
  if (t >= T_TOK) return;
  int* recIdx = (int*)(ws + WS_RECIDX);
  int* cursor = (int*)(ws + WS_CURSOR);
  int* po = (int*)(ws + WS_PO);
  int* tokid = (int*)(ws + WS_TOKID);
  int* pos0 = (int*)(ws + WS_POS0);
  int* pos1 = (int*)(ws + WS_POS1);

  int rec = recIdx[t];
  int e0 = rec & 255, e1 = (rec >> 8) & 255;
  int p0 = atomicAdd(&cursor[e0], 1);
  int r0 = po[e0] + p0;
  tokid[r0] = t; pos0[t] = r0;
  int p1 = atomicAdd(&cursor[e1], 1);
  int r1 = po[e1] + p1;
  tokid[r1] = t; pos1[t] = r1;
}

// ---------------- gather x -> bf16 permuted (zero-padded) -------------------
__global__ __launch_bounds__(256) void k_gather(const float* __restrict__ x,
                                                char* __restrict__ ws) {
  const int* po = (const int*)(ws + WS_PO);
  const int* rc = (const int*)(ws + WS_ROUTE_CNT);
  const int* tokid = (const int*)(ws + WS_TOKID);
  short* xg = (short*)(ws + WS_XG);
  int r = blockIdx.x * 8 + (threadIdx.x >> 5);
  if (r >= po[NE]) return;
  int e = 0;
#pragma unroll
  for (int q = 1; q < NE; ++q) if (r >= po[q]) e = q;
  int l = r - po[e];
  int c0 = (threadIdx.x & 31) * 32;
  short* dst = xg + (size_t)r * H_DIM + c0;
  if (l < rc[e]) {
    const float* src = x + (size_t)tokid[r] * H_DIM + c0;
#pragma unroll
    for (int j = 0; j < 4; ++j) *(short8*)(dst + j * 8) = pack8(src + j * 8);
  } else {
    short8 z = (short8)0;
#pragma unroll
    for (int j = 0; j < 4; ++j) *(short8*)(dst + j * 8) = z;
  }
}

// ---------------- convert weights f32 -> bf16 ------------------------------
#define W_ELEM ((size_t)NE * I_DIM * H_DIM)
#define W_CHUNK (W_ELEM / 8)
__global__ __launch_bounds__(256) void k_convert(const float* __restrict__ wg,
                                                 const float* __restrict__ wu,
                                                 const float* __restrict__ wd,
                                                 char* __restrict__ ws) {
  size_t idx = (size_t)blockIdx.x * 256 + threadIdx.x;
  size_t which = idx / W_CHUNK;
  size_t off = (idx % W_CHUNK) * 8;
  const float* src = (which == 0) ? wg : (which == 1) ? wu : wd;
  short* dst = (short*)(ws + ((which == 0) ? WS_WGB : (which == 1) ? WS_WUB : WS_WDB));
  *(short8*)(dst + off) = pack8(src + off);
}

// ============ 256x256xBK64 8-phase GEMM (T2+T3+T4+T5) ======================
// 512 thr / 8 waves (2M x 4N); acc[8][4]; LDS 128 KB (2 K-tile buffers).
// Per half-iteration (4 phases computing buf h): stage next K-tile into
// buf h^1 as {B0,B1 / B2,B3 / A0,A2 / A1,A3} (2 gloads/phase); counted
// waits vmcnt(4)@q1, vmcnt(2)@q3 land exactly the chunks read 2 phases
// later; never 0 mid-loop. T2 XOR-swizzle on both stage-source and
// ds_read column (involution, rule #21). setprio(1) around MFMA (T5).
// XCD grouping: xcd=idx&7 owns 9 contiguous 256-row tiles; nt-major sweep.
template <int KD, int ND, int EPI>
__global__ __launch_bounds__(512, 2) void k_gemm8(const short* __restrict__ A,
                                                  const short* __restrict__ Bw,
                                                  short* __restrict__ Cb,
                                                  char* __restrict__ ws) {
  const int* po = (const int*)(ws + WS_PO);
  int poNE = po[NE];
  int idx = blockIdx.x;
  int xcd = idx & 7, j = idx >> 3;
  int nt = j / 9;
  int rt = xcd * 9 + (j - nt * 9);      // 72 = 8*9 row tiles of 256
  int r0 = rt * 256;
  if (r0 >= poNE) return;
  int e = 0;
#pragma unroll
  for (int qe = 1; qe < NE; ++qe) if (r0 >= po[qe]) e = qe;

  __shared__ __align__(16) short As[2][256 * 64];
  __shared__ __align__(16) short Bs[2][256 * 64];

  int tid = threadIdx.x, lane = tid & 63, w = tid >> 6;
  int whalf = w >> 2, wq = w & 3;
  int fr = lane & 15, kq8 = (lane >> 4) * 8;
  int csw0 = kq8 ^ ((fr & 7) << 3);
  int csw1 = (32 + kq8) ^ ((fr & 7) << 3);
  int r8 = tid >> 3;
  int scol = ((tid & 7) * 8) ^ ((r8 & 7) << 3);

  const short* Asrc = A + (size_t)r0 * KD + scol;
  const short* Bsrc = Bw + (size_t)e * ((size_t)ND * KD) + (size_t)(nt * 256) * KD + scol;

#define STGA(bb, c, kk) GLOAD16(Asrc + (size_t)((c)*64 + r8) * KD + (kk), &As[bb][(c)*4096 + tid*8])
#define STGB(bb, c, kk) GLOAD16(Bsrc + (size_t)((c)*64 + r8) * KD + (kk), &Bs[bb][(c)*4096 + tid*8])

  f32x4 acc[8][4];
  f32x4 z4 = {0.f, 0.f, 0.f, 0.f};
#pragma unroll
  for (int m = 0; m < 8; ++m)
#pragma unroll
    for (int n = 0; n < 4; ++n) acc[m][n] = z4;

  // prologue: tile 0 -> buf0, order B0,B1,B2,B3,A0,A2,A1,A3; leave A1,A3 in flight
  VMC(0);
  STGB(0, 0, 0); STGB(0, 1, 0); STGB(0, 2, 0); STGB(0, 3, 0);
  STGA(0, 0, 0); STGA(0, 2, 0); STGA(0, 1, 0); STGA(0, 3, 0);
  VMC(2);
  BARX();

  short8 bf[4][2];

#define PH(BB, Q, STG, TAIL)                                                   \
  {                                                                            \
    const short* Ab_ = As[BB];                                                 \
    const short* Bb_ = Bs[BB];                                                 \
    if ((Q) == 0) {                                                            \
      _Pragma("unroll")                                                        \
      for (int n = 0; n < 4; ++n) {                                            \
        bf[n][0] = *(const short8*)&Bb_[(wq * 64 + n * 16 + fr) * 64 + csw0];  \
        bf[n][1] = *(const short8*)&Bb_[(wq * 64 + n * 16 + fr) * 64 + csw1];  \
      }                                                                        \
    }                                                                          \
    short8 a0k0 = *(const short8*)&Ab_[(whalf * 128 + (2 * (Q)) * 16 + fr) * 64 + csw0]; \
    short8 a0k1 = *(const short8*)&Ab_[(whalf * 128 + (2 * (Q)) * 16 + fr) * 64 + csw1]; \
    short8 a1k0 = *(const short8*)&Ab_[(whalf * 128 + (2 * (Q) + 1) * 16 + fr) * 64 + csw0]; \
    short8 a1k1 = *(const short8*)&Ab_[(whalf * 128 + (2 * (Q) + 1) * 16 + fr) * 64 + csw1]; \
    STG;                                                                       \
    BARX();                                                                    \
    __builtin_amdgcn_s_setprio(1);                                             \
    _Pragma("unroll")                                                          \
    for (int n = 0; n < 4; ++n) {                                              \
      acc[2*(Q)][n]   = __builtin_amdgcn_mfma_f32_16x16x32_bf16(a0k0, bf[n][0], acc[2*(Q)][n], 0, 0, 0);   \
      acc[2*(Q)][n]   = __builtin_amdgcn_mfma_f32_16x16x32_bf16(a0k1, bf[n][1], acc[2*(Q)][n], 0, 0, 0);   \
      acc[2*(Q)+1][n] = __builtin_amdgcn_mfma_f32_16x16x32_bf16(a1k0, bf[n][0], acc[2*(Q)+1][n], 0, 0, 0); \
      acc[2*(Q)+1][n] = __builtin_amdgcn_mfma_f32_16x16x32_bf16(a1k1, bf[n][1], acc[2*(Q)+1][n], 0, 0, 0); \
    }                                                                          \
    __builtin_amdgcn_s_setprio(0);                                             \
    TAIL;                                                                      \
    BARX();                                                                    \
  }

  const int NITER = KD / 128;
  for (int it = 0; it < NITER; ++it) {
    bool last = (it == NITER - 1);
    int k1 = it * 128 + 64;
    int k2 = it * 128 + 128;
    // half 0: compute buf0 (tile 2it), stage tile 2it+1 -> buf1
    PH(0, 0, { STGB(1, 0, k1); STGB(1, 1, k1); }, {});
    PH(0, 1, { STGB(1, 2, k1); STGB(1, 3, k1); }, { VMC(4); });
    PH(0, 2, { STGA(1, 0, k1); STGA(1, 2, k1); }, {});
    PH(0, 3, { STGA(1, 1, k1); STGA(1, 3, k1); }, { VMC(2); });
    // half 1: compute buf1 (tile 2it+1), stage tile 2it+2 -> buf0
    PH(1, 0, { if (!last) { STGB(0, 0, k2); STGB(0, 1, k2); } }, {});
    PH(1, 1, { if (!last) { STGB(0, 2, k2); STGB(0, 3, k2); } },
             { if (last) { VMC(0); } else { VMC(4); } });
    PH(1, 2, { if (!last) { STGA(0, 0, k2); STGA(0, 2, k2); } }, {});
    PH(1, 3, { if (!last) { STGA(0, 1, k2); STGA(0, 3, k2); } },
             { if (!last) { VMC(2); } });
  }
#undef PH
#undef STGA
#undef STGB

  int q4 = (lane >> 4) * 4;
#pragma unroll
  for (int m = 0; m < 8; ++m) {
    int row = r0 + whalf * 128 + m * 16 + q4;
#pragma unroll
    for (int n = 0; n < 4; ++n) {
      int col = nt * 256 + wq * 64 + n * 16 + fr;
#pragma unroll
      for (int j2 = 0; j2 < 4; ++j2) {
        size_t oidx = (size_t)(row + j2) * ND + col;
        if (EPI == 1) {
          float g = bf2f(Cb[oidx]);
          float u = acc[m][n][j2];
          Cb[oidx] = f2bf(g / (1.f + expf(-g)) * u);
        } else {
          Cb[oidx] = f2bf(acc[m][n][j2]);
        }
      }
    }
  }
}

// ---------------- combine: out[t] = w0*y[pos0] + w1*y[pos1] ----------------
__global__ __launch_bounds__(256) void k_combine(float* __restrict__ out,
                                                 char* __restrict__ ws) {
  int t = blockIdx.x * 4 + (threadIdx.x >> 6);
  int lane = threadIdx.x & 63;
  const float* recW0 = (const float*)(ws + WS_RECW0);
  const float* recW1 = (const float*)(ws + WS_RECW1);
  const int* pos0 = (const int*)(ws + WS_POS0);
  const int* pos1 = (const int*)(ws + WS_POS1);
  const short* yseg = (const short*)(ws + WS_Y);

  float w0 = recW0[t], w1 = recW1[t];
  const short* y0 = yseg + (size_t)pos0[t] * H_DIM + lane * 16;
  const short* y1 = yseg + (size_t)pos1[t] * H_DIM + lane * 16;
  float* op = out + (size_t)t * H_DIM + lane * 16;

  short8 a0 = *(const short8*)y0;
  short8 a1 = *(const short8*)(y0 + 8);
  short8 b0 = *(const short8*)y1;
  short8 b1 = *(const short8*)(y1 + 8);
#pragma unroll
  for (int j = 0; j < 8; ++j)
    op[j] = w0 * bf2f(a0[j]) + w1 * bf2f(b0[j]);
#pragma unroll
  for (int j = 0; j < 8; ++j)
    op[8 + j] = w0 * bf2f(a1[j]) + w1 * bf2f(b1[j]);
}

extern "C" void kernel_launch(void* const* d_in, const int* in_sizes, int n_in,
                              void* d_out, int out_size, void* d_ws, size_t ws_size,
                              hipStream_t stream) {
  const float* x  = (const float*)d_in[0];
  const float* gw = (const float*)d_in[1];
  const float* wg = (const float*)d_in[2];
  const float* wu = (const float*)d_in[3];
  const float* wd = (const float*)d_in[4];
  float* out = (float*)d_out;
  char* ws = (char*)d_ws;

  hipMemsetAsync(ws, 0, 256, stream);

  const short* xg  = (const short*)(ws + WS_XG);
  const short* wgb = (const short*)(ws + WS_WGB);
  const short* wub = (const short*)(ws + WS_WUB);
  const short* wdb = (const short*)(ws + WS_WDB);
  short* act  = (short*)(ws + WS_ACT);
  short* yseg = (short*)(ws + WS_Y);

  k_convert<<<(int)(3 * W_CHUNK / 256), 256, 0, stream>>>(wg, wu, wd, ws);
  k_router<<<T_TOK / 4, 256, 0, stream>>>(x, gw, ws);
  k_offsets<<<1, 64, 0, stream>>>(ws, out + (size_t)T_TOK * H_DIM);
  k_assign<<<T_TOK / 256, 256, 0, stream>>>(ws);
  k_gather<<<RMAX / 8, 256, 0, stream>>>(x, ws);

  // grids: 8 XCDs x 9 row-tiles (256 rows) x (ND/256) panels
  // gate: act = xg @ wg^T
  k_gemm8<H_DIM, I_DIM, 0><<<8 * 9 * (I_DIM / 256), 512, 0, stream>>>(xg, wgb, act, ws);
  // up (in place): act = silu(act) * (xg @ wu^T)
  k_gemm8<H_DIM, I_DIM, 1><<<8 * 9 * (I_DIM / 256), 512, 0, stream>>>(xg, wub, act, ws);
  // down: yseg = act @ wd^T
  k_gemm8<I_DIM, H_DIM, 2><<<8 * 9 * (H_DIM / 256), 512, 0, stream>>>(act, wdb, yseg, ws);

  k_combine<<<T_TOK / 4, 256, 0, stream>>>(out, ws);
}

// Round 10
// 674.029 us; speedup vs baseline: 1.0487x; 1.0487x over previous
//
#include <hip/hip_runtime.h>
#include <hip/hip_bf16.h>

#define H_DIM 1024
#define I_DIM 2816
#define NE 8
#define T_TOK 8192
#define RMAX 17408

// control ws offsets (bytes)
#define WS_ROUTE_CNT 0
#define WS_CURSOR    32
#define WS_PO        64
#define WS_TOP1      128
#define WS_PSUM      160
#define WS_RECIDX    256
#define WS_RECW0     33024
#define WS_RECW1     65792
#define WS_POS0      98560
#define WS_POS1      131328
#define WS_TOKID     164096

constexpr size_t WS_XG  = 1ull << 20;
constexpr size_t XG_SZ  = (size_t)RMAX * H_DIM * 2;      // 35.7 MB
constexpr size_t W_SZ   = (size_t)NE * I_DIM * H_DIM * 2; // 46.1 MB
constexpr size_t WS_WGB = WS_XG + XG_SZ;
constexpr size_t WS_WUB = WS_WGB + W_SZ;
constexpr size_t WS_WDB = WS_WUB + W_SZ;
constexpr size_t WS_ACT = WS_WDB + W_SZ;                  // 98 MB (gate, then act in-place)
constexpr size_t WS_Y   = WS_XG;                          // yseg overlays xg (xg dead after up-GEMM)

typedef __attribute__((ext_vector_type(8))) short short8;
typedef __attribute__((ext_vector_type(4))) float f32x4;

#define GLOAD16(g, l) __builtin_amdgcn_global_load_lds( \
    (const __attribute__((address_space(1))) void*)(g), \
    (__attribute__((address_space(3))) void*)(l), 16, 0, 0)

static __device__ __forceinline__ short f2bf(float f) {
  return (short)__builtin_bit_cast(unsigned short, (__bf16)f);
}
static __device__ __forceinline__ float bf2f(short s) {
  return __builtin_bit_cast(float, ((unsigned)(unsigned short)s) << 16);
}

static __device__ __forceinline__ short8 pack8(const float* __restrict__ p) {
  float4 a = *(const float4*)p;
  float4 b = *(const float4*)(p + 4);
  short8 v;
  v[0] = f2bf(a.x); v[1] = f2bf(a.y); v[2] = f2bf(a.z); v[3] = f2bf(a.w);
  v[4] = f2bf(b.x); v[5] = f2bf(b.y); v[6] = f2bf(b.z); v[7] = f2bf(b.w);
  return v;
}

// ---------------- fused prep: weight convert (blocks < CONVB) + router -----
#define W_ELEM ((size_t)NE * I_DIM * H_DIM)
#define W_CHUNK (W_ELEM / 8)                   // 2,883,584
#define CONVB (int)(3 * W_CHUNK / 256)         // 33,792 convert blocks
#define PREPB (CONVB + T_TOK / 4)              // + 2048 router blocks

__global__ __launch_bounds__(256) void k_prep(const float* __restrict__ x,
                                              const float* __restrict__ gw,
                                              const float* __restrict__ wg,
                                              const float* __restrict__ wu,
                                              const float* __restrict__ wd,
                                              char* __restrict__ ws) {
  if (blockIdx.x < CONVB) {
    // ---- weight f32 -> bf16 convert ----
    size_t idx = (size_t)blockIdx.x * 256 + threadIdx.x;
    size_t which = idx / W_CHUNK;
    size_t off = (idx % W_CHUNK) * 8;
    const float* src = (which == 0) ? wg : (which == 1) ? wu : wd;
    short* dst = (short*)(ws + ((which == 0) ? WS_WGB : (which == 1) ? WS_WUB : WS_WDB));
    *(short8*)(dst + off) = pack8(src + off);
    return;
  }
  // ---- router: logits -> softmax -> top2 + aux accumulators ----
  int tid = threadIdx.x;
  int lane = tid & 63;
  int wv = tid >> 6;
  int t = (blockIdx.x - CONVB) * 4 + wv;

  float acc[NE];
#pragma unroll
  for (int e = 0; e < NE; ++e) acc[e] = 0.f;
  const float* xr = x + (size_t)t * H_DIM;
#pragma unroll
  for (int k = 0; k < H_DIM / 64; ++k) {
    float xv = xr[k * 64 + lane];
#pragma unroll
    for (int e = 0; e < NE; ++e) acc[e] += xv * gw[e * H_DIM + k * 64 + lane];
  }
#pragma unroll
  for (int e = 0; e < NE; ++e) {
#pragma unroll
    for (int off = 32; off; off >>= 1) acc[e] += __shfl_xor(acc[e], off);
  }

  __shared__ float s_ps[NE], s_c1[NE];
  __shared__ int s_rc[NE];
  if (tid < NE) { s_ps[tid] = 0.f; s_c1[tid] = 0.f; s_rc[tid] = 0; }
  __syncthreads();

  int* recIdx = (int*)(ws + WS_RECIDX);
  float* recW0 = (float*)(ws + WS_RECW0);
  float* recW1 = (float*)(ws + WS_RECW1);

  if (lane == 0) {
    float mx = acc[0];
#pragma unroll
    for (int e = 1; e < NE; ++e) mx = fmaxf(mx, acc[e]);
    float p[NE], s = 0.f;
#pragma unroll
    for (int e = 0; e < NE; ++e) { p[e] = expf(acc[e] - mx); s += p[e]; }
    float inv = 1.f / s;
#pragma unroll
    for (int e = 0; e < NE; ++e) p[e] *= inv;
    int i0 = 0;
#pragma unroll
    for (int e = 1; e < NE; ++e) if (p[e] > p[i0]) i0 = e;
    int i1 = (i0 == 0) ? 1 : 0;
#pragma unroll
    for (int e = 0; e < NE; ++e) if (e != i0 && p[e] > p[i1]) i1 = e;
    float w0 = p[i0], w1 = p[i1];
    float sm = fmaxf(w0 + w1, 1e-8f);
    w0 /= sm; w1 /= sm;
    recIdx[t] = i0 | (i1 << 8);
    recW0[t] = w0;
    recW1[t] = w1;
    atomicAdd(&s_c1[i0], 1.f);
#pragma unroll
    for (int e = 0; e < NE; ++e) atomicAdd(&s_ps[e], p[e]);
    atomicAdd(&s_rc[i0], 1);
    atomicAdd(&s_rc[i1], 1);
  }
  __syncthreads();
  if (tid < NE) {
    atomicAdd((float*)(ws + WS_PSUM) + tid, s_ps[tid]);
    atomicAdd((float*)(ws + WS_TOP1) + tid, s_c1[tid]);
    atomicAdd((int*)(ws + WS_ROUTE_CNT) + tid, s_rc[tid]);
  }
}

// ---------------- offsets (128-padded) + aux -------------------------------
__global__ void k_offsets(char* __restrict__ ws, float* __restrict__ out_aux) {
  if (threadIdx.x == 0) {
    int* rc = (int*)(ws + WS_ROUTE_CNT);
    int* po = (int*)(ws + WS_PO);
    int acc = 0;
    for (int e = 0; e < NE; ++e) {
      po[e] = acc;
      acc += ((rc[e] + 127) / 128) * 128;
    }
    po[NE] = acc;
    float* c1 = (float*)(ws + WS_TOP1);
    float* ps = (float*)(ws + WS_PSUM);
    float aux = 0.f;
    for (int e = 0; e < NE; ++e)
      aux += (c1[e] / (float)T_TOK) * (ps[e] / (float)T_TOK);
    out_aux[0] = aux * (float)NE;
  }
}

// ---------------- assign ----------------------------------------------------
__global__ __launch_bounds__(256) void k_assign(char* __restrict__ ws) {
  int t = blockIdx.x * 256 + threadIdx.x;
  if (t >= T_TOK) return;
  int* recIdx = (int*)(ws + WS_RECIDX);
  int* cursor = (int*)(ws + WS_CURSOR);
  int* po = (int*)(ws + WS_PO);
  int* tokid = (int*)(ws + WS_TOKID);
  int* pos0 = (int*)(ws + WS_POS0);
  int* pos1 = (int*)(ws + WS_POS1);

  int rec = recIdx[t];
  int e0 = rec & 255, e1 = (rec >> 8) & 255;
  int p0 = atomicAdd(&cursor[e0], 1);
  int r0 = po[e0] + p0;
  tokid[r0] = t; pos0[t] = r0;
  int p1 = atomicAdd(&cursor[e1], 1);
  int r1 = po[e1] + p1;
  tokid[r1] = t; pos1[t] = r1;
}

// ---------------- gather x -> bf16 permuted (zero-padded) -------------------
__global__ __launch_bounds__(256) void k_gather(const float* __restrict__ x,
                                                char* __restrict__ ws) {
  const int* po = (const int*)(ws + WS_PO);
  const int* rc = (const int*)(ws + WS_ROUTE_CNT);
  const int* tokid = (const int*)(ws + WS_TOKID);
  short* xg = (short*)(ws + WS_XG);
  int r = blockIdx.x * 8 + (threadIdx.x >> 5);
  if (r >= po[NE]) return;
  int e = 0;
#pragma unroll
  for (int q = 1; q < NE; ++q) if (r >= po[q]) e = q;
  int l = r - po[e];
  int c0 = (threadIdx.x & 31) * 32;
  short* dst = xg + (size_t)r * H_DIM + c0;
  if (l < rc[e]) {
    const float* src = x + (size_t)tokid[r] * H_DIM + c0;
#pragma unroll
    for (int j = 0; j < 4; ++j) *(short8*)(dst + j * 8) = pack8(src + j * 8);
  } else {
    short8 z = (short8)0;
#pragma unroll
    for (int j = 0; j < 4; ++j) *(short8*)(dst + j * 8) = z;
  }
}

// ============ m97-exact 128x128xBK64 GEMM (round-4/5 structure) ============
// Single-buffer, 2-barrier K-loop; global_load_lds width=16; (256,4) keeps
// 60 VGPR + 64 AGPR within the 128-reg/wave budget (4 waves/EU).
// Grid mapping (round-6, proven FETCH 400->252->150 MB): each XCD
// (blockIdx&7) owns 17 contiguous row-tiles (A chunk ~4.25 MB, L2-resident)
// and sweeps B panels nt-major within its group (B panel 256 KB, L2-hot).
// EPI 0: store bf16 (gate -> act). EPI 1: act = silu(act)*acc in place.
// EPI 2: store bf16 (down -> yseg).
template <int KD, int ND, int EPI>
__global__ __launch_bounds__(256, 4) void k_gemm(const short* __restrict__ A,
                                                 const short* __restrict__ Bw,
                                                 short* __restrict__ Cb,
                                                 char* __restrict__ ws) {
  const int* po = (const int*)(ws + WS_PO);
  int poNE = po[NE];

  int idx = blockIdx.x;
  int xcd = idx & 7, j = idx >> 3;       // j in [0, 17 * ND/128)
  int nt = j / 17;
  int rt = xcd * 17 + (j - nt * 17);     // 136 = 8*17 row tiles

  int r0 = rt * 128;
  if (r0 >= poNE) return;
  int e = 0;
#pragma unroll
  for (int qe = 1; qe < NE; ++qe) if (r0 >= po[qe]) e = qe;

  const short* Ab = A + (size_t)r0 * KD;
  const short* Bb = Bw + (size_t)e * ((size_t)ND * KD) + (size_t)(nt * 128) * KD;

  __shared__ __align__(16) short As[128 * 64];
  __shared__ __align__(16) short Bs[128 * 64];

  int tid = threadIdx.x, lane = tid & 63, w = tid >> 6;
  int wr = (w >> 1) * 64, wc = (w & 1) * 64;
  int fr = lane & 15, kq = (lane >> 4) * 8;
  int srow = tid >> 3, scol = (tid & 7) * 8;

  f32x4 acc[4][4];
  f32x4 z4 = {0.f, 0.f, 0.f, 0.f};
#pragma unroll
  for (int m = 0; m < 4; ++m)
#pragma unroll
    for (int n = 0; n < 4; ++n) acc[m][n] = z4;

  for (int kk = 0; kk < KD; kk += 64) {
#pragma unroll
    for (int c = 0; c < 4; ++c) {
      GLOAD16(Ab + (size_t)(c * 32 + srow) * KD + kk + scol, &As[c * 2048 + tid * 8]);
      GLOAD16(Bb + (size_t)(c * 32 + srow) * KD + kk + scol, &Bs[c * 2048 + tid * 8]);
    }
    __syncthreads();
#pragma unroll
    for (int ks = 0; ks < 2; ++ks) {
      short8 af[4];
#pragma unroll
      for (int m = 0; m < 4; ++m)
        af[m] = *(const short8*)&As[(wr + m * 16 + fr) * 64 + ks * 32 + kq];
#pragma unroll
      for (int n = 0; n < 4; ++n) {
        short8 bf_ = *(const short8*)&Bs[(wc + n * 16 + fr) * 64 + ks * 32 + kq];
#pragma unroll
        for (int m = 0; m < 4; ++m)
          acc[m][n] = __builtin_amdgcn_mfma_f32_16x16x32_bf16(af[m], bf_, acc[m][n], 0, 0, 0);
      }
    }
    __syncthreads();
  }

  int q4 = (lane >> 4) * 4;
#pragma unroll
  for (int m = 0; m < 4; ++m) {
#pragma unroll
    for (int n = 0; n < 4; ++n) {
      int col = nt * 128 + wc + n * 16 + fr;
#pragma unroll
      for (int j2 = 0; j2 < 4; ++j2) {
        size_t oidx = (size_t)(r0 + wr + m * 16 + q4 + j2) * ND + col;
        if (EPI == 1) {
          float g = bf2f(Cb[oidx]);
          float u = acc[m][n][j2];
          Cb[oidx] = f2bf(g / (1.f + expf(-g)) * u);
        } else {
          Cb[oidx] = f2bf(acc[m][n][j2]);
        }
      }
    }
  }
}

// ---------------- combine: out[t] = w0*y[pos0] + w1*y[pos1] ----------------
__global__ __launch_bounds__(256) void k_combine(float* __restrict__ out,
                                                 char* __restrict__ ws) {
  int t = blockIdx.x * 4 + (threadIdx.x >> 6);
  int lane = threadIdx.x & 63;
  const float* recW0 = (const float*)(ws + WS_RECW0);
  const float* recW1 = (const float*)(ws + WS_RECW1);
  const int* pos0 = (const int*)(ws + WS_POS0);
  const int* pos1 = (const int*)(ws + WS_POS1);
  const short* yseg = (const short*)(ws + WS_Y);

  float w0 = recW0[t], w1 = recW1[t];
  const short* y0 = yseg + (size_t)pos0[t] * H_DIM + lane * 16;
  const short* y1 = yseg + (size_t)pos1[t] * H_DIM + lane * 16;
  float* op = out + (size_t)t * H_DIM + lane * 16;

  short8 a0 = *(const short8*)y0;
  short8 a1 = *(const short8*)(y0 + 8);
  short8 b0 = *(const short8*)y1;
  short8 b1 = *(const short8*)(y1 + 8);
#pragma unroll
  for (int j = 0; j < 8; ++j)
    op[j] = w0 * bf2f(a0[j]) + w1 * bf2f(b0[j]);
#pragma unroll
  for (int j = 0; j < 8; ++j)
    op[8 + j] = w0 * bf2f(a1[j]) + w1 * bf2f(b1[j]);
}

extern "C" void kernel_launch(void* const* d_in, const int* in_sizes, int n_in,
                              void* d_out, int out_size, void* d_ws, size_t ws_size,
                              hipStream_t stream) {
  const float* x  = (const float*)d_in[0];
  const float* gw = (const float*)d_in[1];
  const float* wg = (const float*)d_in[2];
  const float* wu = (const float*)d_in[3];
  const float* wd = (const float*)d_in[4];
  float* out = (float*)d_out;
  char* ws = (char*)d_ws;

  hipMemsetAsync(ws, 0, 256, stream);

  const short* xg  = (const short*)(ws + WS_XG);
  const short* wgb = (const short*)(ws + WS_WGB);
  const short* wub = (const short*)(ws + WS_WUB);
  const short* wdb = (const short*)(ws + WS_WDB);
  short* act  = (short*)(ws + WS_ACT);
  short* yseg = (short*)(ws + WS_Y);

  // fused: weight convert + router in one dispatch (independent work,
  // router overlaps under convert's HBM stream; one fewer launch gap)
  k_prep<<<PREPB, 256, 0, stream>>>(x, gw, wg, wu, wd, ws);
  k_offsets<<<1, 64, 0, stream>>>(ws, out + (size_t)T_TOK * H_DIM);
  k_assign<<<T_TOK / 256, 256, 0, stream>>>(ws);
  k_gather<<<RMAX / 8, 256, 0, stream>>>(x, ws);

  // grids: 8 XCD groups x 17 row-tiles x (ND/128) panels
  // gate: act = xg @ wg^T
  k_gemm<H_DIM, I_DIM, 0><<<8 * 17 * (I_DIM / 128), 256, 0, stream>>>(xg, wgb, act, ws);
  // up (in place): act = silu(act) * (xg @ wu^T)
  k_gemm<H_DIM, I_DIM, 1><<<8 * 17 * (I_DIM / 128), 256, 0, stream>>>(xg, wub, act, ws);
  // down: yseg = act @ wd^T
  k_gemm<I_DIM, H_DIM, 2><<<8 * 17 * (H_DIM / 128), 256, 0, stream>>>(act, wdb, yseg, ws);

  k_combine<<<T_TOK / 4, 256, 0, stream>>>(out, ws);
}